// Round 3
// baseline (817.843 us; speedup 1.0000x reference)
//
#include <hip/hip_runtime.h>
#include <hip/hip_bf16.h>
#include <math.h>

#define B_ 2
#define T_ 2048
#define H_ 16
#define D_ 64
#define E_ 1024
#define O_ 1024
#define BT_ 4096
// 0.125 * log2(e): folds softmax's exp->exp2 conversion into the Q projection
#define SCALE_Q 0.18033688011f

typedef __attribute__((ext_vector_type(8))) short bf8;
typedef __attribute__((ext_vector_type(4))) float f4;

static __device__ __forceinline__ unsigned short f2bf(float f) {
  unsigned u = __builtin_bit_cast(unsigned, f);
  u += 0x7FFFu + ((u >> 16) & 1u);
  return (unsigned short)(u >> 16);
}

// packed fp32x2 -> bf16x2 (RNE), lo = src0
static __device__ __forceinline__ unsigned cvtpk_bf(float lo, float hi) {
  unsigned r;
  asm("v_cvt_pk_bf16_f32 %0, %1, %2" : "=v"(r) : "v"(lo), "v"(hi));
  return r;
}

// 8 fp32 -> 8 bf16 via 4x v_cvt_pk_bf16_f32 (was ~32 VALU ops of manual RNE)
static __device__ __forceinline__ uint4 cvt8(float4 a, float4 b) {
  uint4 v;
  v.x = cvtpk_bf(a.x, a.y);
  v.y = cvtpk_bf(a.z, a.w);
  v.z = cvtpk_bf(b.x, b.y);
  v.w = cvtpk_bf(b.z, b.w);
  return v;
}

static __device__ __forceinline__ f4 mfma16(bf8 a, bf8 b, f4 c) {
  return __builtin_amdgcn_mfma_f32_16x16x32_bf16(a, b, c, 0, 0, 0);
}

// raw v_exp_f32: computes 2^x in one instruction
static __device__ __forceinline__ float ex2(float x) {
  float r;
  asm("v_exp_f32 %0, %1" : "=v"(r) : "v"(x));
  return r;
}

// ---------------------------------------------------------------------------
// Fused Q/K/V projection: C = X (BTxE fp32) * W^T -> dst bf16 (B,H,T,D).
// blockIdx.z selects {q,k,v}. block tile 64x128, 4 waves, BK=32.
// ---------------------------------------------------------------------------
__global__ __launch_bounds__(256) void qkv_gemm(const float* __restrict__ Xq,
                                                const float* __restrict__ Xk,
                                                const float* __restrict__ Xv,
                                                const float* __restrict__ Wq,
                                                const float* __restrict__ Wk,
                                                const float* __restrict__ Wv,
                                                unsigned short* __restrict__ dq,
                                                unsigned short* __restrict__ dk,
                                                unsigned short* __restrict__ dv) {
  __shared__ __align__(16) unsigned short lA[64 * 40];
  __shared__ __align__(16) unsigned short lB[128 * 40];
  const int z = blockIdx.z;
  const float* X = (z == 0) ? Xq : (z == 1) ? Xk : Xv;
  const float* W = (z == 0) ? Wq : (z == 1) ? Wk : Wv;
  unsigned short* dst = (z == 0) ? dq : (z == 1) ? dk : dv;
  const float scale = (z == 0) ? SCALE_Q : 1.0f;

  const int tid = threadIdx.x;
  const int bx = blockIdx.x, by = blockIdx.y;
  const int lane = tid & 63, w = tid >> 6;
  const int l15 = lane & 15, qd = lane >> 4;
  const int wr = (w >> 1) * 32, wc = (w & 1) * 64;

  const int ar = tid >> 2, akc = (tid & 3) << 3;   // A stage: 64 rows x 4 chunks(8f)
  const int br = tid >> 1, bkc = (tid & 1) << 4;   // B stage: 128 rows x 2 chunks(16f)
  const float* aptr = X + (size_t)(bx * 64 + ar) * E_ + akc;
  const float* bptr = W + (size_t)(by * 128 + br) * E_ + bkc;

  f4 acc[2][4];
#pragma unroll
  for (int i = 0; i < 2; ++i)
#pragma unroll
    for (int j = 0; j < 4; ++j) acc[i][j] = (f4){0.f, 0.f, 0.f, 0.f};

  for (int k0 = 0; k0 < E_; k0 += 32) {
    __syncthreads();
    {
      const float4* p = (const float4*)aptr;
      *(uint4*)&lA[ar * 40 + akc] = cvt8(p[0], p[1]);
    }
    {
      const float4* p = (const float4*)bptr;
      *(uint4*)&lB[br * 40 + bkc] = cvt8(p[0], p[1]);
      *(uint4*)&lB[br * 40 + bkc + 8] = cvt8(p[2], p[3]);
    }
    aptr += 32; bptr += 32;
    __syncthreads();

    bf8 af[2], bfr[4];
#pragma unroll
    for (int rt = 0; rt < 2; ++rt)
      af[rt] = *(const bf8*)&lA[(wr + rt * 16 + l15) * 40 + qd * 8];
#pragma unroll
    for (int ct = 0; ct < 4; ++ct)
      bfr[ct] = *(const bf8*)&lB[(wc + ct * 16 + l15) * 40 + qd * 8];
#pragma unroll
    for (int rt = 0; rt < 2; ++rt)
#pragma unroll
      for (int ct = 0; ct < 4; ++ct)
        acc[rt][ct] = mfma16(af[rt], bfr[ct], acc[rt][ct]);
  }

  // epilogue: scatter to (B,H,T,D) bf16, scaled
#pragma unroll
  for (int rt = 0; rt < 2; ++rt)
#pragma unroll
    for (int ct = 0; ct < 4; ++ct)
#pragma unroll
      for (int r = 0; r < 4; ++r) {
        int m = bx * 64 + wr + rt * 16 + qd * 4 + r;  // token row
        int n = by * 128 + wc + ct * 16 + l15;        // feature
        int b = m >> 11, t = m & 2047;
        int h = n >> 6, d = n & 63;
        dst[((size_t)(b * H_ + h) * T_ + t) * D_ + d] = f2bf(acc[rt][ct][r] * scale);
      }
}

// ---------------------------------------------------------------------------
// merged transposes: blocks [0,1024): vh (B,H,T,D) -> vt (B,H,D,T), 64x64 tiles
//                    blocks [1024,1280): proj (H*D,O) fp32 -> projT (O,H*D) bf16
// ---------------------------------------------------------------------------
__global__ __launch_bounds__(256) void transpose_all(const unsigned short* __restrict__ vh,
                                                     unsigned short* __restrict__ vt,
                                                     const float* __restrict__ pk,
                                                     unsigned short* __restrict__ pt) {
  __shared__ __align__(16) unsigned short lT[64 * 72];
  const int tid = threadIdx.x;
  if (blockIdx.x < 1024) {
    const int bh = blockIdx.x >> 5;
    const int t0 = (blockIdx.x & 31) * 64;
    const unsigned short* src = vh + (size_t)bh * T_ * D_ + (size_t)t0 * D_;
#pragma unroll
    for (int i = 0; i < 2; ++i) {
      int c = tid + i * 256;
      int row = c >> 3, dc = (c & 7) << 3;
      *(uint4*)&lT[row * 72 + dc] = *(const uint4*)(src + row * D_ + dc);
    }
    __syncthreads();
    unsigned short* dstp = vt + (size_t)bh * D_ * T_;
#pragma unroll
    for (int i = 0; i < 2; ++i) {
      int c = tid + i * 256;
      int d = c >> 3, tc = (c & 7) << 3;
      union { unsigned short s[8]; uint4 v; } u;
#pragma unroll
      for (int j = 0; j < 8; ++j) u.s[j] = lT[(tc + j) * 72 + d];
      *(uint4*)(dstp + (size_t)d * T_ + t0 + tc) = u.v;
    }
  } else {
    const int bx = blockIdx.x - 1024;
    const int hd0 = (bx >> 4) * 64;
    const int o0 = (bx & 15) * 64;
#pragma unroll
    for (int i = 0; i < 2; ++i) {
      int c = tid + i * 256;
      int row = c >> 3, oc = (c & 7) << 3;
      const float4* p = (const float4*)(pk + (size_t)(hd0 + row) * O_ + o0 + oc);
      *(uint4*)&lT[row * 72 + oc] = cvt8(p[0], p[1]);
    }
    __syncthreads();
#pragma unroll
    for (int i = 0; i < 2; ++i) {
      int c = tid + i * 256;
      int orow = c >> 3, hc = (c & 7) << 3;
      union { unsigned short s[8]; uint4 v; } u;
#pragma unroll
      for (int j = 0; j < 8; ++j) u.s[j] = lT[(hc + j) * 72 + orow];
      *(uint4*)(pt + (size_t)(o0 + orow) * E_ + hd0 + hc) = u.v;
    }
  }
}

// ---------------------------------------------------------------------------
// attention, swapped-QK^T, QBLK=128 (8 waves), KVBLK=64.
// Per block: one (b,h), 128 query rows. Each 64-row K/V stage now serves 128
// q-rows (half the global K traffic / barriers per unit work vs QBLK=64).
// S^T = mfma(Kfrag, Qfrag): lane(l15,qd) holds S[k=qd*4+r][q=l15] per subtile.
// Q is in log2-e domain (SCALE_Q), so softmax uses raw v_exp_f32 (2^x).
// pass 1: per-lane deferred max + sumexp2. pass 2: recompute S, write P, PV.
// ---------------------------------------------------------------------------
__global__ __launch_bounds__(512) void attention(const unsigned short* __restrict__ qh,
                                                 const unsigned short* __restrict__ kh,
                                                 const unsigned short* __restrict__ vt,
                                                 float* __restrict__ attn,
                                                 unsigned short* __restrict__ mh) {
  __shared__ __align__(16) unsigned short lK[64 * 72];
  __shared__ __align__(16) unsigned short lV[64 * 72];
  __shared__ __align__(16) unsigned short lP[8 * 16 * 72];

  const int tid = threadIdx.x;
  const int bh = blockIdx.x >> 4;
  const int n0 = (blockIdx.x & 15) * 128;
  const int lane = tid & 63, w = tid >> 6;   // w in 0..7
  const int l15 = lane & 15, qd = lane >> 4;

  const unsigned short* qbase = qh + ((size_t)bh * T_ + n0) * D_;
  const unsigned short* kbase = kh + (size_t)bh * T_ * D_;
  const unsigned short* vbase = vt + (size_t)bh * D_ * T_;

  // Q fragments straight from global
  const bf8 aq0 = *(const bf8*)(qbase + (w * 16 + l15) * D_ + qd * 8);
  const bf8 aq1 = *(const bf8*)(qbase + (w * 16 + l15) * D_ + 32 + qd * 8);

  const int srow = tid >> 3, scol = (tid & 7) << 3;  // 512 thr stage 64x128B in one shot

  // ---- pass 1: per-lane stats (k-slice is lane-local in swapped layout) ----
  float mL = -INFINITY, lL = 0.f;
  for (int m0 = 0; m0 < T_; m0 += 64) {
    __syncthreads();
    *(uint4*)&lK[srow * 72 + scol] = *(const uint4*)(kbase + (size_t)(m0 + srow) * D_ + scol);
    __syncthreads();
    f4 s[4];
#pragma unroll
    for (int kk = 0; kk < 4; ++kk) {
      bf8 k0 = *(const bf8*)&lK[(kk * 16 + l15) * 72 + qd * 8];
      bf8 k1 = *(const bf8*)&lK[(kk * 16 + l15) * 72 + 32 + qd * 8];
      f4 t = (f4){0.f, 0.f, 0.f, 0.f};
      t = mfma16(k0, aq0, t);
      t = mfma16(k1, aq1, t);
      s[kk] = t;
    }
    float tm = s[0][0];
#pragma unroll
    for (int kk = 0; kk < 4; ++kk)
#pragma unroll
      for (int r = 0; r < 4; ++r) tm = fmaxf(tm, s[kk][r]);
    float nm = fmaxf(mL, tm);
    lL *= ex2(mL - nm);   // == 1 when max didn't grow; ex2(-inf)=0 handles first iter
    mL = nm;
#pragma unroll
    for (int kk = 0; kk < 4; ++kk)
#pragma unroll
      for (int r = 0; r < 4; ++r) lL += ex2(s[kk][r] - mL);
  }

  // merge the 4 lanes (qd groups) holding the same q-row: xor 16, 32
  float mrow = mL, lrow = lL;
#pragma unroll
  for (int off = 16; off < 64; off <<= 1) {
    float om = __shfl_xor(mrow, off);
    float ol = __shfl_xor(lrow, off);
    float nm = fmaxf(mrow, om);
    lrow = lrow * ex2(mrow - nm) + ol * ex2(om - nm);
    mrow = nm;
  }
  const float invl = 1.0f / lrow;

  // ---- pass 2: recompute S, write normalized P (f4 nontemporal), P*V ----
  f4 o[4];
#pragma unroll
  for (int dt = 0; dt < 4; ++dt) o[dt] = (f4){0.f, 0.f, 0.f, 0.f};

  float* attnrow = attn + ((size_t)bh * T_ + n0 + w * 16 + l15) * T_ + qd * 4;
  unsigned short* lPw = lP + w * 16 * 72;

  for (int m0 = 0; m0 < T_; m0 += 64) {
    __syncthreads();
    *(uint4*)&lK[srow * 72 + scol] = *(const uint4*)(kbase + (size_t)(m0 + srow) * D_ + scol);
    *(uint4*)&lV[srow * 72 + scol] = *(const uint4*)(vbase + (size_t)srow * T_ + m0 + scol);
    __syncthreads();
    f4 s[4];
#pragma unroll
    for (int kk = 0; kk < 4; ++kk) {
      bf8 k0 = *(const bf8*)&lK[(kk * 16 + l15) * 72 + qd * 8];
      bf8 k1 = *(const bf8*)&lK[(kk * 16 + l15) * 72 + 32 + qd * 8];
      f4 t = (f4){0.f, 0.f, 0.f, 0.f};
      t = mfma16(k0, aq0, t);
      t = mfma16(k1, aq1, t);
      s[kk] = t;
    }
#pragma unroll
    for (int kk = 0; kk < 4; ++kk) {
      float p0 = ex2(s[kk][0] - mrow) * invl;
      float p1 = ex2(s[kk][1] - mrow) * invl;
      float p2 = ex2(s[kk][2] - mrow) * invl;
      float p3 = ex2(s[kk][3] - mrow) * invl;
      f4 pf = (f4){p0, p1, p2, p3};
      __builtin_nontemporal_store(pf, (f4*)(attnrow + m0 + kk * 16));
      uint2 pb;
      pb.x = cvtpk_bf(p0, p1);
      pb.y = cvtpk_bf(p2, p3);
      *(uint2*)&lPw[l15 * 72 + kk * 16 + qd * 4] = pb;  // P[q=l15][k=kk*16+qd*4..+3]
    }
    // same-wave LDS RAW (lPw slice is per-wave): no barrier needed, lgkmcnt orders
    bf8 ap0 = *(const bf8*)&lPw[l15 * 72 + qd * 8];
    bf8 ap1 = *(const bf8*)&lPw[l15 * 72 + 32 + qd * 8];
#pragma unroll
    for (int dt = 0; dt < 4; ++dt) {
      bf8 bv0 = *(const bf8*)&lV[(dt * 16 + l15) * 72 + qd * 8];
      bf8 bv1 = *(const bf8*)&lV[(dt * 16 + l15) * 72 + 32 + qd * 8];
      o[dt] = mfma16(ap0, bv0, o[dt]);
      o[dt] = mfma16(ap1, bv1, o[dt]);
    }
  }

  // epilogue: mh (B,T,H*D) bf16
  const int b = bh >> 4, h = bh & 15;
#pragma unroll
  for (int dt = 0; dt < 4; ++dt)
#pragma unroll
    for (int r = 0; r < 4; ++r) {
      int t = n0 + w * 16 + qd * 4 + r;
      int d = dt * 16 + l15;
      mh[(size_t)(b * T_ + t) * E_ + h * D_ + d] = f2bf(o[dt][r]);
    }
}

// ---------------------------------------------------------------------------
// out = mh (BTxE bf16) * projT^T (OxE bf16, row-major) + bias -> fp32
// ---------------------------------------------------------------------------
__global__ __launch_bounds__(256) void out_gemm(const unsigned short* __restrict__ A,
                                                const unsigned short* __restrict__ Bm,
                                                const float* __restrict__ bias,
                                                float* __restrict__ Cout) {
  __shared__ __align__(16) unsigned short lA[64 * 40];
  __shared__ __align__(16) unsigned short lB[128 * 40];
  const int tid = threadIdx.x;
  const int bx = blockIdx.x, by = blockIdx.y;
  const int lane = tid & 63, w = tid >> 6;
  const int l15 = lane & 15, qd = lane >> 4;
  const int wr = (w >> 1) * 32, wc = (w & 1) * 64;

  const int ar = tid >> 2, akc = (tid & 3) << 3;
  const unsigned short* aptr = A + (size_t)(bx * 64 + ar) * E_ + akc;

  f4 acc[2][4];
#pragma unroll
  for (int i = 0; i < 2; ++i)
#pragma unroll
    for (int j = 0; j < 4; ++j) acc[i][j] = (f4){0.f, 0.f, 0.f, 0.f};

  for (int k0 = 0; k0 < E_; k0 += 32) {
    __syncthreads();
    *(uint4*)&lA[ar * 40 + akc] = *(const uint4*)aptr;
#pragma unroll
    for (int i = 0; i < 2; ++i) {
      int c = tid + i * 256;
      int br = c >> 2, bkc = (c & 3) << 3;
      *(uint4*)&lB[br * 40 + bkc] =
          *(const uint4*)(Bm + (size_t)(by * 128 + br) * E_ + k0 + bkc);
    }
    aptr += 32;
    __syncthreads();

    bf8 af[2], bfr[4];
#pragma unroll
    for (int rt = 0; rt < 2; ++rt)
      af[rt] = *(const bf8*)&lA[(wr + rt * 16 + l15) * 40 + qd * 8];
#pragma unroll
    for (int ct = 0; ct < 4; ++ct)
      bfr[ct] = *(const bf8*)&lB[(wc + ct * 16 + l15) * 40 + qd * 8];
#pragma unroll
    for (int rt = 0; rt < 2; ++rt)
#pragma unroll
      for (int ct = 0; ct < 4; ++ct)
        acc[rt][ct] = mfma16(af[rt], bfr[ct], acc[rt][ct]);
  }

#pragma unroll
  for (int ct = 0; ct < 4; ++ct) {
    int n = by * 128 + wc + ct * 16 + l15;
    float bv = bias[n];
#pragma unroll
    for (int rt = 0; rt < 2; ++rt)
#pragma unroll
      for (int r = 0; r < 4; ++r) {
        int m = bx * 64 + wr + rt * 16 + qd * 4 + r;
        __builtin_nontemporal_store(acc[rt][ct][r] + bv, &Cout[(size_t)m * O_ + n]);
      }
  }
}

// ---------------------------------------------------------------------------
extern "C" void kernel_launch(void* const* d_in, const int* in_sizes, int n_in,
                              void* d_out, int out_size, void* d_ws, size_t ws_size,
                              hipStream_t stream) {
  const float* query = (const float*)d_in[0];
  const float* key_i = (const float*)d_in[1];
  const float* value = (const float*)d_in[2];
  const float* Wq = (const float*)d_in[3];
  const float* Wk = (const float*)d_in[4];
  const float* Wv = (const float*)d_in[5];
  const float* pk = (const float*)d_in[6];
  const float* pb = (const float*)d_in[7];

  float* out = (float*)d_out;
  float* attn = out + (size_t)BT_ * O_;

  unsigned short* ws = (unsigned short*)d_ws;
  unsigned short* qh = ws;                       // 4M bf16
  unsigned short* kh = qh + (size_t)4194304;     // 4M
  unsigned short* vh = kh + (size_t)4194304;     // 4M (reused as mh after transpose)
  unsigned short* vtb = vh + (size_t)4194304;    // 4M
  unsigned short* pt = vtb + (size_t)4194304;    // 1M
  unsigned short* mhb = vh;                      // reuse: vh dead after transpose_v

  dim3 blk(256, 1, 1);
  hipLaunchKernelGGL(qkv_gemm, dim3(64, 8, 3), blk, 0, stream,
                     query, key_i, value, Wq, Wk, Wv, qh, kh, vh);
  hipLaunchKernelGGL(transpose_all, dim3(1280), blk, 0, stream, vh, vtb, pk, pt);
  hipLaunchKernelGGL(attention, dim3(512), dim3(512, 1, 1), 0, stream, qh, kh, vtb, attn, mhb);
  hipLaunchKernelGGL(out_gemm, dim3(64, 8), blk, 0, stream, mhb, pt, pb, out);
}

// Round 4
// 790.348 us; speedup vs baseline: 1.0348x; 1.0348x over previous
//
#include <hip/hip_runtime.h>
#include <hip/hip_bf16.h>
#include <math.h>

#define B_ 2
#define T_ 2048
#define H_ 16
#define D_ 64
#define E_ 1024
#define O_ 1024
#define BT_ 4096
// 0.125 * log2(e): folds softmax's exp->exp2 conversion into the Q projection
#define SCALE_Q 0.18033688011f

typedef __attribute__((ext_vector_type(8))) short bf8;
typedef __attribute__((ext_vector_type(4))) float f4;

static __device__ __forceinline__ unsigned short f2bf(float f) {
  unsigned u = __builtin_bit_cast(unsigned, f);
  u += 0x7FFFu + ((u >> 16) & 1u);
  return (unsigned short)(u >> 16);
}

// packed fp32x2 -> bf16x2 (RNE), lo = src0
static __device__ __forceinline__ unsigned cvtpk_bf(float lo, float hi) {
  unsigned r;
  asm("v_cvt_pk_bf16_f32 %0, %1, %2" : "=v"(r) : "v"(lo), "v"(hi));
  return r;
}

// 8 fp32 -> 8 bf16 via 4x v_cvt_pk_bf16_f32
static __device__ __forceinline__ uint4 cvt8(float4 a, float4 b) {
  uint4 v;
  v.x = cvtpk_bf(a.x, a.y);
  v.y = cvtpk_bf(a.z, a.w);
  v.z = cvtpk_bf(b.x, b.y);
  v.w = cvtpk_bf(b.z, b.w);
  return v;
}

static __device__ __forceinline__ f4 mfma16(bf8 a, bf8 b, f4 c) {
  return __builtin_amdgcn_mfma_f32_16x16x32_bf16(a, b, c, 0, 0, 0);
}

// raw v_exp_f32: computes 2^x in one instruction
static __device__ __forceinline__ float ex2(float x) {
  float r;
  asm("v_exp_f32 %0, %1" : "=v"(r) : "v"(x));
  return r;
}

// ---------------------------------------------------------------------------
// Fused Q/K/V projection: C = X (BTxE fp32) * W^T -> dst bf16 (B,H,T,D).
// blockIdx.z selects {q,k,v}. block tile 64x128, 4 waves, BK=32.
// T14: next K-tile's global loads issued right after the consume barrier so
// latency hides under the MFMA cluster.
// ---------------------------------------------------------------------------
__global__ __launch_bounds__(256) void qkv_gemm(const float* __restrict__ Xq,
                                                const float* __restrict__ Xk,
                                                const float* __restrict__ Xv,
                                                const float* __restrict__ Wq,
                                                const float* __restrict__ Wk,
                                                const float* __restrict__ Wv,
                                                unsigned short* __restrict__ dq,
                                                unsigned short* __restrict__ dk,
                                                unsigned short* __restrict__ dv) {
  __shared__ __align__(16) unsigned short lA[64 * 40];
  __shared__ __align__(16) unsigned short lB[128 * 40];
  const int z = blockIdx.z;
  const float* X = (z == 0) ? Xq : (z == 1) ? Xk : Xv;
  const float* W = (z == 0) ? Wq : (z == 1) ? Wk : Wv;
  unsigned short* dst = (z == 0) ? dq : (z == 1) ? dk : dv;
  const float scale = (z == 0) ? SCALE_Q : 1.0f;

  const int tid = threadIdx.x;
  const int bx = blockIdx.x, by = blockIdx.y;
  const int lane = tid & 63, w = tid >> 6;
  const int l15 = lane & 15, qd = lane >> 4;
  const int wr = (w >> 1) * 32, wc = (w & 1) * 64;

  const int ar = tid >> 2, akc = (tid & 3) << 3;   // A stage: 64 rows x 4 chunks(8f)
  const int br = tid >> 1, bkc = (tid & 1) << 4;   // B stage: 128 rows x 2 chunks(16f)
  const float* abase = X + (size_t)(bx * 64 + ar) * E_ + akc;
  const float* bbase = W + (size_t)(by * 128 + br) * E_ + bkc;

  // prefetch k0=0 tile into regs
  float4 pa0 = ((const float4*)abase)[0], pa1 = ((const float4*)abase)[1];
  float4 pb0 = ((const float4*)bbase)[0], pb1 = ((const float4*)bbase)[1];
  float4 pb2 = ((const float4*)bbase)[2], pb3 = ((const float4*)bbase)[3];

  f4 acc[2][4];
#pragma unroll
  for (int i = 0; i < 2; ++i)
#pragma unroll
    for (int j = 0; j < 4; ++j) acc[i][j] = (f4){0.f, 0.f, 0.f, 0.f};

  for (int k0 = 0; k0 < E_; k0 += 32) {
    __syncthreads();
    *(uint4*)&lA[ar * 40 + akc] = cvt8(pa0, pa1);
    *(uint4*)&lB[br * 40 + bkc] = cvt8(pb0, pb1);
    *(uint4*)&lB[br * 40 + bkc + 8] = cvt8(pb2, pb3);
    __syncthreads();

    // T14: issue next-tile loads now; they complete during the MFMA cluster
    const int kn = (k0 + 32) & (E_ - 1);   // wraps on last iter (values unused)
    pa0 = ((const float4*)(abase + kn))[0]; pa1 = ((const float4*)(abase + kn))[1];
    pb0 = ((const float4*)(bbase + kn))[0]; pb1 = ((const float4*)(bbase + kn))[1];
    pb2 = ((const float4*)(bbase + kn))[2]; pb3 = ((const float4*)(bbase + kn))[3];

    bf8 af[2], bfr[4];
#pragma unroll
    for (int rt = 0; rt < 2; ++rt)
      af[rt] = *(const bf8*)&lA[(wr + rt * 16 + l15) * 40 + qd * 8];
#pragma unroll
    for (int ct = 0; ct < 4; ++ct)
      bfr[ct] = *(const bf8*)&lB[(wc + ct * 16 + l15) * 40 + qd * 8];
#pragma unroll
    for (int rt = 0; rt < 2; ++rt)
#pragma unroll
      for (int ct = 0; ct < 4; ++ct)
        acc[rt][ct] = mfma16(af[rt], bfr[ct], acc[rt][ct]);
  }

  // epilogue: scatter to (B,H,T,D) bf16, scaled
#pragma unroll
  for (int rt = 0; rt < 2; ++rt)
#pragma unroll
    for (int ct = 0; ct < 4; ++ct)
#pragma unroll
      for (int r = 0; r < 4; ++r) {
        int m = bx * 64 + wr + rt * 16 + qd * 4 + r;  // token row
        int n = by * 128 + wc + ct * 16 + l15;        // feature
        int b = m >> 11, t = m & 2047;
        int h = n >> 6, d = n & 63;
        dst[((size_t)(b * H_ + h) * T_ + t) * D_ + d] = f2bf(acc[rt][ct][r] * scale);
      }
}

// ---------------------------------------------------------------------------
// merged transposes: blocks [0,1024): vh (B,H,T,D) -> vt (B,H,D,T), 64x64 tiles
//                    blocks [1024,1280): proj (H*D,O) fp32 -> projT (O,H*D) bf16
// ---------------------------------------------------------------------------
__global__ __launch_bounds__(256) void transpose_all(const unsigned short* __restrict__ vh,
                                                     unsigned short* __restrict__ vt,
                                                     const float* __restrict__ pk,
                                                     unsigned short* __restrict__ pt) {
  __shared__ __align__(16) unsigned short lT[64 * 72];
  const int tid = threadIdx.x;
  if (blockIdx.x < 1024) {
    const int bh = blockIdx.x >> 5;
    const int t0 = (blockIdx.x & 31) * 64;
    const unsigned short* src = vh + (size_t)bh * T_ * D_ + (size_t)t0 * D_;
#pragma unroll
    for (int i = 0; i < 2; ++i) {
      int c = tid + i * 256;
      int row = c >> 3, dc = (c & 7) << 3;
      *(uint4*)&lT[row * 72 + dc] = *(const uint4*)(src + row * D_ + dc);
    }
    __syncthreads();
    unsigned short* dstp = vt + (size_t)bh * D_ * T_;
#pragma unroll
    for (int i = 0; i < 2; ++i) {
      int c = tid + i * 256;
      int d = c >> 3, tc = (c & 7) << 3;
      union { unsigned short s[8]; uint4 v; } u;
#pragma unroll
      for (int j = 0; j < 8; ++j) u.s[j] = lT[(tc + j) * 72 + d];
      *(uint4*)(dstp + (size_t)d * T_ + t0 + tc) = u.v;
    }
  } else {
    const int bx = blockIdx.x - 1024;
    const int hd0 = (bx >> 4) * 64;
    const int o0 = (bx & 15) * 64;
#pragma unroll
    for (int i = 0; i < 2; ++i) {
      int c = tid + i * 256;
      int row = c >> 3, oc = (c & 7) << 3;
      const float4* p = (const float4*)(pk + (size_t)(hd0 + row) * O_ + o0 + oc);
      *(uint4*)&lT[row * 72 + oc] = cvt8(p[0], p[1]);
    }
    __syncthreads();
#pragma unroll
    for (int i = 0; i < 2; ++i) {
      int c = tid + i * 256;
      int orow = c >> 3, hc = (c & 7) << 3;
      union { unsigned short s[8]; uint4 v; } u;
#pragma unroll
      for (int j = 0; j < 8; ++j) u.s[j] = lT[(hc + j) * 72 + orow];
      *(uint4*)(pt + (size_t)(o0 + orow) * E_ + hd0 + hc) = u.v;
    }
  }
}

// ---------------------------------------------------------------------------
// attention, swapped-QK^T, QBLK=64 (4 waves, R2 shape), KVBLK=64.
// T14 async-STAGE: next K/V tile's global loads are issued right after the
// consume barrier; HBM latency hides under QK^T + softmax + PV.
// XCD swizzle: the 32 blocks sharing one (b,h)'s K/V become XCD-contiguous.
// Q in log2-e domain (SCALE_Q); softmax uses raw v_exp_f32 (2^x).
// ---------------------------------------------------------------------------
__global__ __launch_bounds__(256) void attention(const unsigned short* __restrict__ qh,
                                                 const unsigned short* __restrict__ kh,
                                                 const unsigned short* __restrict__ vt,
                                                 float* __restrict__ attn,
                                                 unsigned short* __restrict__ mh) {
  __shared__ __align__(16) unsigned short lK[64 * 72];
  __shared__ __align__(16) unsigned short lV[64 * 72];
  __shared__ __align__(16) unsigned short lP[4 * 16 * 72];

  const int tid = threadIdx.x;
  // XCD-aware swizzle (1024 blocks, 8 XCDs, bijective since 1024%8==0)
  const int swz = (blockIdx.x & 7) * 128 + (blockIdx.x >> 3);
  const int bh = swz >> 5;
  const int n0 = (swz & 31) * 64;
  const int lane = tid & 63, w = tid >> 6;
  const int l15 = lane & 15, qd = lane >> 4;

  const unsigned short* qbase = qh + ((size_t)bh * T_ + n0) * D_;
  const unsigned short* kbase = kh + (size_t)bh * T_ * D_;
  const unsigned short* vbase = vt + (size_t)bh * D_ * T_;

  // Q fragments straight from global
  const bf8 aq0 = *(const bf8*)(qbase + (w * 16 + l15) * D_ + qd * 8);
  const bf8 aq1 = *(const bf8*)(qbase + (w * 16 + l15) * D_ + 32 + qd * 8);

  const int srow = tid >> 3, scol = (tid & 7) << 3;  // 32 rows x 8 chunks per shot
  const unsigned short* kst = kbase + (size_t)srow * D_ + scol;

  // ---- pass 1: per-lane stats (k-slice is lane-local in swapped layout) ----
  uint4 kr0 = *(const uint4*)kst;
  uint4 kr1 = *(const uint4*)(kst + 32 * D_);
  float mL = -INFINITY, lL = 0.f;
  for (int m0 = 0; m0 < T_; m0 += 64) {
    __syncthreads();
    *(uint4*)&lK[srow * 72 + scol] = kr0;
    *(uint4*)&lK[(srow + 32) * 72 + scol] = kr1;
    __syncthreads();
    const int mn = (m0 + 64) & (T_ - 1);   // wraps on last iter (unused values)
    kr0 = *(const uint4*)(kst + (size_t)mn * D_);
    kr1 = *(const uint4*)(kst + (size_t)(mn + 32) * D_);
    f4 s[4];
#pragma unroll
    for (int kk = 0; kk < 4; ++kk) {
      bf8 k0 = *(const bf8*)&lK[(kk * 16 + l15) * 72 + qd * 8];
      bf8 k1 = *(const bf8*)&lK[(kk * 16 + l15) * 72 + 32 + qd * 8];
      f4 t = (f4){0.f, 0.f, 0.f, 0.f};
      t = mfma16(k0, aq0, t);
      t = mfma16(k1, aq1, t);
      s[kk] = t;
    }
    float tm = s[0][0];
#pragma unroll
    for (int kk = 0; kk < 4; ++kk)
#pragma unroll
      for (int r = 0; r < 4; ++r) tm = fmaxf(tm, s[kk][r]);
    float nm = fmaxf(mL, tm);
    lL *= ex2(mL - nm);   // == 1 when max didn't grow; ex2(-inf)=0 handles first iter
    mL = nm;
#pragma unroll
    for (int kk = 0; kk < 4; ++kk)
#pragma unroll
      for (int r = 0; r < 4; ++r) lL += ex2(s[kk][r] - mL);
  }

  // merge the 4 lanes (qd groups) holding the same q-row: xor 16, 32
  float mrow = mL, lrow = lL;
#pragma unroll
  for (int off = 16; off < 64; off <<= 1) {
    float om = __shfl_xor(mrow, off);
    float ol = __shfl_xor(lrow, off);
    float nm = fmaxf(mrow, om);
    lrow = lrow * ex2(mrow - nm) + ol * ex2(om - nm);
    mrow = nm;
  }
  const float invl = 1.0f / lrow;

  // ---- pass 2: recompute S, write normalized P (f4 nontemporal), P*V ----
  f4 o[4];
#pragma unroll
  for (int dt = 0; dt < 4; ++dt) o[dt] = (f4){0.f, 0.f, 0.f, 0.f};

  float* attnrow = attn + ((size_t)bh * T_ + n0 + w * 16 + l15) * T_ + qd * 4;
  unsigned short* lPw = lP + w * 16 * 72;
  const unsigned short* vst = vbase + (size_t)srow * T_ + scol;

  kr0 = *(const uint4*)kst;
  kr1 = *(const uint4*)(kst + 32 * D_);
  uint4 vr0 = *(const uint4*)vst;
  uint4 vr1 = *(const uint4*)(vst + 32 * T_);

  for (int m0 = 0; m0 < T_; m0 += 64) {
    __syncthreads();
    *(uint4*)&lK[srow * 72 + scol] = kr0;
    *(uint4*)&lK[(srow + 32) * 72 + scol] = kr1;
    *(uint4*)&lV[srow * 72 + scol] = vr0;
    *(uint4*)&lV[(srow + 32) * 72 + scol] = vr1;
    __syncthreads();
    const int mn = (m0 + 64) & (T_ - 1);
    kr0 = *(const uint4*)(kst + (size_t)mn * D_);
    kr1 = *(const uint4*)(kst + (size_t)(mn + 32) * D_);
    vr0 = *(const uint4*)(vst + mn);
    vr1 = *(const uint4*)(vst + 32 * T_ + mn);

    f4 s[4];
#pragma unroll
    for (int kk = 0; kk < 4; ++kk) {
      bf8 k0 = *(const bf8*)&lK[(kk * 16 + l15) * 72 + qd * 8];
      bf8 k1 = *(const bf8*)&lK[(kk * 16 + l15) * 72 + 32 + qd * 8];
      f4 t = (f4){0.f, 0.f, 0.f, 0.f};
      t = mfma16(k0, aq0, t);
      t = mfma16(k1, aq1, t);
      s[kk] = t;
    }
#pragma unroll
    for (int kk = 0; kk < 4; ++kk) {
      float p0 = ex2(s[kk][0] - mrow) * invl;
      float p1 = ex2(s[kk][1] - mrow) * invl;
      float p2 = ex2(s[kk][2] - mrow) * invl;
      float p3 = ex2(s[kk][3] - mrow) * invl;
      f4 pf = (f4){p0, p1, p2, p3};
      __builtin_nontemporal_store(pf, (f4*)(attnrow + m0 + kk * 16));
      uint2 pb;
      pb.x = cvtpk_bf(p0, p1);
      pb.y = cvtpk_bf(p2, p3);
      *(uint2*)&lPw[l15 * 72 + kk * 16 + qd * 4] = pb;  // P[q=l15][k=kk*16+qd*4..+3]
    }
    // same-wave LDS RAW (lPw slice is per-wave): no barrier needed, lgkmcnt orders
    bf8 ap0 = *(const bf8*)&lPw[l15 * 72 + qd * 8];
    bf8 ap1 = *(const bf8*)&lPw[l15 * 72 + 32 + qd * 8];
#pragma unroll
    for (int dt = 0; dt < 4; ++dt) {
      bf8 bv0 = *(const bf8*)&lV[(dt * 16 + l15) * 72 + qd * 8];
      bf8 bv1 = *(const bf8*)&lV[(dt * 16 + l15) * 72 + 32 + qd * 8];
      o[dt] = mfma16(ap0, bv0, o[dt]);
      o[dt] = mfma16(ap1, bv1, o[dt]);
    }
  }

  // epilogue: mh (B,T,H*D) bf16
  const int b = bh >> 4, h = bh & 15;
#pragma unroll
  for (int dt = 0; dt < 4; ++dt)
#pragma unroll
    for (int r = 0; r < 4; ++r) {
      int t = n0 + w * 16 + qd * 4 + r;
      int d = dt * 16 + l15;
      mh[(size_t)(b * T_ + t) * E_ + h * D_ + d] = f2bf(o[dt][r]);
    }
}

// ---------------------------------------------------------------------------
// out = mh (BTxE bf16) * projT^T (OxE bf16, row-major) + bias -> fp32
// T14 reg-prefetch on both A and B staging.
// ---------------------------------------------------------------------------
__global__ __launch_bounds__(256) void out_gemm(const unsigned short* __restrict__ A,
                                                const unsigned short* __restrict__ Bm,
                                                const float* __restrict__ bias,
                                                float* __restrict__ Cout) {
  __shared__ __align__(16) unsigned short lA[64 * 40];
  __shared__ __align__(16) unsigned short lB[128 * 40];
  const int tid = threadIdx.x;
  const int bx = blockIdx.x, by = blockIdx.y;
  const int lane = tid & 63, w = tid >> 6;
  const int l15 = lane & 15, qd = lane >> 4;
  const int wr = (w >> 1) * 32, wc = (w & 1) * 64;

  const int ar = tid >> 2, akc = (tid & 3) << 3;
  const unsigned short* abase = A + (size_t)(bx * 64 + ar) * E_ + akc;
  const int br0 = tid >> 2, bkc0 = (tid & 3) << 3;
  const int br1 = (tid + 256) >> 2, bkc1 = bkc0;
  const unsigned short* bbase0 = Bm + (size_t)(by * 128 + br0) * E_ + bkc0;
  const unsigned short* bbase1 = Bm + (size_t)(by * 128 + br1) * E_ + bkc1;

  uint4 pa = *(const uint4*)abase;
  uint4 pb0 = *(const uint4*)bbase0;
  uint4 pb1 = *(const uint4*)bbase1;

  f4 acc[2][4];
#pragma unroll
  for (int i = 0; i < 2; ++i)
#pragma unroll
    for (int j = 0; j < 4; ++j) acc[i][j] = (f4){0.f, 0.f, 0.f, 0.f};

  for (int k0 = 0; k0 < E_; k0 += 32) {
    __syncthreads();
    *(uint4*)&lA[ar * 40 + akc] = pa;
    *(uint4*)&lB[br0 * 40 + bkc0] = pb0;
    *(uint4*)&lB[br1 * 40 + bkc1] = pb1;
    __syncthreads();
    const int kn = (k0 + 32) & (E_ - 1);
    pa = *(const uint4*)(abase + kn);
    pb0 = *(const uint4*)(bbase0 + kn);
    pb1 = *(const uint4*)(bbase1 + kn);

    bf8 af[2], bfr[4];
#pragma unroll
    for (int rt = 0; rt < 2; ++rt)
      af[rt] = *(const bf8*)&lA[(wr + rt * 16 + l15) * 40 + qd * 8];
#pragma unroll
    for (int ct = 0; ct < 4; ++ct)
      bfr[ct] = *(const bf8*)&lB[(wc + ct * 16 + l15) * 40 + qd * 8];
#pragma unroll
    for (int rt = 0; rt < 2; ++rt)
#pragma unroll
      for (int ct = 0; ct < 4; ++ct)
        acc[rt][ct] = mfma16(af[rt], bfr[ct], acc[rt][ct]);
  }

#pragma unroll
  for (int ct = 0; ct < 4; ++ct) {
    int n = by * 128 + wc + ct * 16 + l15;
    float bv = bias[n];
#pragma unroll
    for (int rt = 0; rt < 2; ++rt)
#pragma unroll
      for (int r = 0; r < 4; ++r) {
        int m = bx * 64 + wr + rt * 16 + qd * 4 + r;
        __builtin_nontemporal_store(acc[rt][ct][r] + bv, &Cout[(size_t)m * O_ + n]);
      }
  }
}

// ---------------------------------------------------------------------------
extern "C" void kernel_launch(void* const* d_in, const int* in_sizes, int n_in,
                              void* d_out, int out_size, void* d_ws, size_t ws_size,
                              hipStream_t stream) {
  const float* query = (const float*)d_in[0];
  const float* key_i = (const float*)d_in[1];
  const float* value = (const float*)d_in[2];
  const float* Wq = (const float*)d_in[3];
  const float* Wk = (const float*)d_in[4];
  const float* Wv = (const float*)d_in[5];
  const float* pk = (const float*)d_in[6];
  const float* pb = (const float*)d_in[7];

  float* out = (float*)d_out;
  float* attn = out + (size_t)BT_ * O_;

  unsigned short* ws = (unsigned short*)d_ws;
  unsigned short* qh = ws;                       // 4M bf16
  unsigned short* kh = qh + (size_t)4194304;     // 4M
  unsigned short* vh = kh + (size_t)4194304;     // 4M (reused as mh after transpose)
  unsigned short* vtb = vh + (size_t)4194304;    // 4M
  unsigned short* pt = vtb + (size_t)4194304;    // 1M
  unsigned short* mhb = vh;                      // reuse: vh dead after transpose_v

  dim3 blk(256, 1, 1);
  hipLaunchKernelGGL(qkv_gemm, dim3(64, 8, 3), blk, 0, stream,
                     query, key_i, value, Wq, Wk, Wv, qh, kh, vh);
  hipLaunchKernelGGL(transpose_all, dim3(1280), blk, 0, stream, vh, vtb, pk, pt);
  hipLaunchKernelGGL(attention, dim3(1024), blk, 0, stream, qh, kh, vtb, attn, mhb);
  hipLaunchKernelGGL(out_gemm, dim3(64, 8), blk, 0, stream, mhb, pt, pb, out);
}